// Round 4
// baseline (401.800 us; speedup 1.0000x reference)
//
#include <hip/hip_runtime.h>
#include <hip/hip_bf16.h>

typedef __bf16 bf16;
typedef __bf16 bf16x4 __attribute__((ext_vector_type(4)));
typedef __bf16 bf16x8 __attribute__((ext_vector_type(8)));
typedef float  f32x4  __attribute__((ext_vector_type(4)));

#define AS1 __attribute__((address_space(1)))
#define AS3 __attribute__((address_space(3)))

__device__ __forceinline__ void load16_to_lds(const bf16* g, bf16* l) {
    __builtin_amdgcn_global_load_lds((const AS1 unsigned int*)g,
                                     (AS3 unsigned int*)l, 16, 0, 0);
}

// ---------------------------------------------------------------------------
// prep_w: conv_w fp32 [o][1024] -> bf16 same layout. Must precede fused_x.
__global__ __launch_bounds__(256) void prep_w(const float* __restrict__ w,
                                              bf16* __restrict__ wb) {
    int idx = (blockIdx.x * 256 + threadIdx.x) * 4;   // grid 256
    const float4 v = *(const float4*)(w + idx);
    bf16x4 o; o[0]=(bf16)v.x; o[1]=(bf16)v.y; o[2]=(bf16)v.z; o[3]=(bf16)v.w;
    *(bf16x4*)(wb + idx) = o;
}

// ---------------------------------------------------------------------------
// tile layout: [row 0..63][264 bf16], with 8-elem chunks XOR-swizzled by
// (row>>2)&7 so phase1's scalar b16 writes are ~2-way instead of 8-way
// bank-conflicted. All readers apply the same XOR; chunks stay 16B-contig.
__device__ __forceinline__ int tix(int row, int chunk, int lo) {
    return row * 264 + (((chunk ^ ((row >> 2) & 7)) << 3) | lo);
}

// fused_x: per block (b, coarse row j, 32-wide w-tile):
//   phase1: x fp32 -> LDS tile [64 pos][256 c] bf16 (burst 16 loads first)
//   phase2: Haar details -> cT bf16 [mc][d*256+c]
//   phase3: y1[o][pos] = W[:,0:256] . tile  -- K=256 GEMM, W-frags direct
//           from L2 with depth-1 software pipeline; no barriers in K-loop.
__global__ __launch_bounds__(256, 4) void fused_x(const float* __restrict__ x,
                                                  const bf16* __restrict__ W,
                                                  bf16* __restrict__ cT,
                                                  bf16* __restrict__ y1) {
    __shared__ bf16 tile[64 * 264];
    const int bid = blockIdx.x;               // grid 2048
    const int wt = bid & 3, j = (bid >> 2) & 63, b = bid >> 8;
    const int t = threadIdx.x;
    const int w0 = wt * 32;
    const int wave = t >> 6, lane = t & 63;
    const int quad = lane >> 4, l16 = lane & 15;
    const int wo = wave * 64;

    // prefetch W fragments for kk=0 (L2-resident; latency hidden by phase1)
    bf16x8 wf_cur[4], wf_nxt[4];
    #pragma unroll
    for (int jj = 0; jj < 4; ++jj)
        wf_cur[jj] = *(const bf16x8*)(W +
            (size_t)(wo + jj * 16 + l16) * 1024 + quad * 8);

    // phase1a: burst all 16 float4 loads (independent, in flight together)
    float4 v[16];
    #pragma unroll
    for (int i = 0; i < 16; ++i) {
        int g = i * 256 + t;
        int c = g >> 4, rem = g & 15;
        int dlt = rem >> 3, w4 = rem & 7;
        v[i] = *(const float4*)(x +
            ((((size_t)b * 256 + c) * 128 + (2 * j + dlt)) * 128 + w0 + w4 * 4));
    }
    // phase1b: convert + swizzled LDS writes (rows pos..pos+3 share swizzle)
    #pragma unroll
    for (int i = 0; i < 16; ++i) {
        int g = i * 256 + t;
        int c = g >> 4, rem = g & 15;
        int dlt = rem >> 3, w4 = rem & 7;
        int pos = dlt * 32 + w4 * 4;
        int cs = tix(pos, c >> 3, c & 7) - pos * 264;   // column after swizzle
        tile[(pos + 0) * 264 + cs] = (bf16)v[i].x;
        tile[(pos + 1) * 264 + cs] = (bf16)v[i].y;
        tile[(pos + 2) * 264 + cs] = (bf16)v[i].z;
        tile[(pos + 3) * 264 + cs] = (bf16)v[i].w;
    }
    __syncthreads();

    // phase2: Haar -> cT. 16 coarse cols * 32 c-chunks.
    for (int i = 0; i < 2; ++i) {
        int q = i * 256 + t;
        int cq = q & 31, kc = q >> 5;
        int r0 = 2 * kc, r1 = 2 * kc + 1, r2 = 32 + 2 * kc, r3 = 33 + 2 * kc;
        bf16x8 vp = *(const bf16x8*)&tile[tix(r0, cq, 0)];
        bf16x8 vq = *(const bf16x8*)&tile[tix(r1, cq, 0)];
        bf16x8 vr = *(const bf16x8*)&tile[tix(r2, cq, 0)];
        bf16x8 vs = *(const bf16x8*)&tile[tix(r3, cq, 0)];
        bf16x8 oh, ov, od;
        #pragma unroll
        for (int e = 0; e < 8; ++e) {
            float p = (float)vp[e], qq = (float)vq[e];
            float r = (float)vr[e], s = (float)vs[e];
            oh[e] = (bf16)(0.5f * (p + qq - r - s));
            ov[e] = (bf16)(0.5f * (p - qq + r - s));
            od[e] = (bf16)(0.5f * (p - qq - r + s));
        }
        size_t row = ((size_t)b * 4096 + j * 64 + wt * 16 + kc) * 768;
        *(bf16x8*)(cT + row + 0 * 256 + cq * 8) = oh;
        *(bf16x8*)(cT + row + 1 * 256 + cq * 8) = ov;
        *(bf16x8*)(cT + row + 2 * 256 + cq * 8) = od;
    }

    // phase3: wave = 64 pos x 64 o. MFMA(xf, wf): D.row=pos, D.col=o.
    f32x4 acc[4][4] = {};
    #pragma unroll
    for (int kk = 0; kk < 256; kk += 32) {
        if (kk < 224) {
            #pragma unroll
            for (int jj = 0; jj < 4; ++jj)
                wf_nxt[jj] = *(const bf16x8*)(W +
                    (size_t)(wo + jj * 16 + l16) * 1024 + kk + 32 + quad * 8);
        }
        bf16x8 xf[4];
        #pragma unroll
        for (int i2 = 0; i2 < 4; ++i2)
            xf[i2] = *(const bf16x8*)&tile[tix(i2 * 16 + l16,
                                               (kk >> 3) + quad, 0)];
        #pragma unroll
        for (int i2 = 0; i2 < 4; ++i2)
            #pragma unroll
            for (int jj = 0; jj < 4; ++jj)
                acc[i2][jj] = __builtin_amdgcn_mfma_f32_16x16x32_bf16(
                    xf[i2], wf_cur[jj], acc[i2][jj], 0, 0, 0);
        #pragma unroll
        for (int jj = 0; jj < 4; ++jj) wf_cur[jj] = wf_nxt[jj];
    }

    // epilogue: pos = i*16+quad*4+r (4 consecutive w), o = wo+jj*16+l16
    #pragma unroll
    for (int i = 0; i < 4; ++i) {
        int p = i * 16 + quad * 4;
        int h = 2 * j + (p >> 5), wc = w0 + (p & 31);
        #pragma unroll
        for (int jj = 0; jj < 4; ++jj) {
            int o = wo + jj * 16 + l16;
            bf16x4 vv;
            #pragma unroll
            for (int r = 0; r < 4; ++r) vv[r] = (bf16)acc[i][jj][r];
            *(bf16x4*)(y1 + ((size_t)b * 256 + o) * 16384 + h * 128 + wc) = vv;
        }
    }
}

// ---------------------------------------------------------------------------
// gemm2: z[o][mc] = W[:,256:1024] . cT, K=768. 128x128 tile; cT staged via
// global_load_lds; W-frags direct from L2 with depth-1 pipeline.
__global__ __launch_bounds__(256, 4) void gemm2(const bf16* __restrict__ W,
                                                const bf16* __restrict__ cT,
                                                bf16* __restrict__ z) {
    __shared__ bf16 Xt[128 * 32];
    const int bid = blockIdx.x;               // grid 512
    const int m0 = (bid & 255) * 128, o0 = (bid >> 8) * 128;
    const int t = threadIdx.x;
    const int wave = t >> 6, lane = t & 63;
    const int quad = lane >> 4, l16 = lane & 15;
    const int wo = (wave >> 1) * 64, wm = (wave & 1) * 64;
    const int r_in = lane >> 2, cch = lane & 3;

    f32x4 acc[4][4] = {};
    const bf16* wbase = W + (size_t)o0 * 1024 + 256;
    const bf16* xbase = cT + (size_t)m0 * 768;

    bf16x8 af_cur[4], af_nxt[4];
    #pragma unroll
    for (int i = 0; i < 4; ++i)
        af_cur[i] = *(const bf16x8*)(wbase +
            (size_t)(wo + i * 16 + l16) * 1024 + quad * 8);

    #pragma unroll 2
    for (int kk = 0; kk < 768; kk += 32) {
        #pragma unroll
        for (int i = 0; i < 2; ++i) {
            int rblk = wave * 2 + i;
            int row = rblk * 16 + r_in;
            load16_to_lds(xbase + (size_t)row * 768 + kk + cch * 8,
                          &Xt[rblk * 512 + lane * 8]);
        }
        __syncthreads();
        if (kk < 736) {
            #pragma unroll
            for (int i = 0; i < 4; ++i)
                af_nxt[i] = *(const bf16x8*)(wbase +
                    (size_t)(wo + i * 16 + l16) * 1024 + kk + 32 + quad * 8);
        }
        bf16x8 bfr[4];
        #pragma unroll
        for (int jj = 0; jj < 4; ++jj)
            bfr[jj] = *(const bf16x8*)&Xt[(wm + jj * 16 + l16) * 32 + quad * 8];
        #pragma unroll
        for (int i = 0; i < 4; ++i)
            #pragma unroll
            for (int jj = 0; jj < 4; ++jj)
                acc[i][jj] = __builtin_amdgcn_mfma_f32_16x16x32_bf16(
                    bfr[jj], af_cur[i], acc[i][jj], 0, 0, 0);
        __syncthreads();
        #pragma unroll
        for (int i = 0; i < 4; ++i) af_cur[i] = af_nxt[i];
    }

    #pragma unroll
    for (int i = 0; i < 4; ++i) {
        int o = o0 + wo + i * 16 + l16;
        #pragma unroll
        for (int jj = 0; jj < 4; ++jj) {
            int m = m0 + wm + jj * 16 + quad * 4;
            int bb = m >> 12, mp = m & 4095;
            bf16x4 vv;
            #pragma unroll
            for (int r = 0; r < 4; ++r) vv[r] = (bf16)acc[i][jj][r];
            *(bf16x4*)(z + ((size_t)bb * 256 + o) * 4096 + mp) = vv;
        }
    }
}

// ---------------------------------------------------------------------------
// Bilinear 2x upsample weights: 0.75/0.25 per axis, edge-clamped (== jax).
__device__ __forceinline__ void load_zplane(const bf16* zp, float* zs, int t) {
    for (int i = 0; i < 2; ++i) {
        int idx = (i * 256 + t) * 8;
        int j = idx >> 6, k = idx & 63;
        bf16x8 v = *(const bf16x8*)(zp + idx);
        #pragma unroll
        for (int e = 0; e < 8; ++e) zs[j * 65 + k + e] = (float)v[e];
    }
}

__device__ __forceinline__ void up8(const float* zs, int base, float* u) {
    int h = base >> 7, w0 = base & 127;
    int j0 = h >> 1;
    int jn = (h & 1) ? min(j0 + 1, 63) : max(j0 - 1, 0);
    int K = w0 >> 1;
    float z0[6], z1[6];
    #pragma unroll
    for (int d = 0; d < 6; ++d) {
        int kc = min(max(K - 1 + d, 0), 63);
        z0[d] = zs[j0 * 65 + kc];
        z1[d] = zs[jn * 65 + kc];
    }
    #pragma unroll
    for (int e = 0; e < 8; ++e) {
        int a = (e >> 1) + 1;
        int bb = (e & 1) ? a + 1 : a - 1;
        u[e] = 0.5625f * z0[a] + 0.1875f * (z0[bb] + z1[a]) + 0.0625f * z1[bb];
    }
}

__global__ __launch_bounds__(256) void stats_k(const bf16* __restrict__ y1,
                                               const bf16* __restrict__ z,
                                               float* __restrict__ stats) {
    __shared__ float zs[64 * 65];
    __shared__ float red[8];
    const int bid = blockIdx.x;               // grid 2048 = b*256 + o
    const int o = bid & 255, b = bid >> 8;
    const int t = threadIdx.x;
    const bf16* zp = z + ((size_t)b * 256 + o) * 4096;
    const bf16* yp = y1 + ((size_t)b * 256 + o) * 16384;
    load_zplane(zp, zs, t);
    __syncthreads();
    float s = 0.f, ss = 0.f;
    for (int i = 0; i < 8; ++i) {
        int base = (i * 256 + t) * 8;
        float u[8];
        up8(zs, base, u);
        bf16x8 yv = *(const bf16x8*)(yp + base);
        #pragma unroll
        for (int e = 0; e < 8; ++e) {
            float y = (float)yv[e] + u[e];
            s += y; ss += y * y;
        }
    }
    #pragma unroll
    for (int off = 32; off > 0; off >>= 1) {
        s += __shfl_down(s, off);
        ss += __shfl_down(ss, off);
    }
    if ((t & 63) == 0) { red[t >> 6] = s; red[4 + (t >> 6)] = ss; }
    __syncthreads();
    if (t == 0) {
        atomicAdd(&stats[o],       red[0] + red[1] + red[2] + red[3]);
        atomicAdd(&stats[256 + o], red[4] + red[5] + red[6] + red[7]);
    }
}

__global__ __launch_bounds__(256) void finalize_k(float* __restrict__ stats,
                                                  const float* __restrict__ gamma,
                                                  const float* __restrict__ beta) {
    int o = threadIdx.x;                       // 1 block, 256 threads
    const float n = 131072.f;
    float mean = stats[o] / n;
    float var = stats[256 + o] / n - mean * mean;
    float rstd = rsqrtf(var + 1e-5f);
    float sc = rstd * gamma[o];
    stats[512 + o] = sc;
    stats[768 + o] = beta[o] - mean * sc;
}

__global__ __launch_bounds__(256) void apply_k(const bf16* __restrict__ y1,
                                               const bf16* __restrict__ z,
                                               const float* __restrict__ stats,
                                               float* __restrict__ out) {
    __shared__ float zs[64 * 65];
    const int bid = blockIdx.x;
    const int o = bid & 255, b = bid >> 8;
    const int t = threadIdx.x;
    const bf16* zp = z + ((size_t)b * 256 + o) * 4096;
    const bf16* yp = y1 + ((size_t)b * 256 + o) * 16384;
    float* op = out + ((size_t)b * 256 + o) * 16384;
    const float sc = stats[512 + o], sh = stats[768 + o];
    load_zplane(zp, zs, t);
    __syncthreads();
    for (int i = 0; i < 8; ++i) {
        int base = (i * 256 + t) * 8;
        float u[8];
        up8(zs, base, u);
        bf16x8 yv = *(const bf16x8*)(yp + base);
        float4 o0, o1;
        o0.x = fmaxf(fmaf((float)yv[0] + u[0], sc, sh), 0.f);
        o0.y = fmaxf(fmaf((float)yv[1] + u[1], sc, sh), 0.f);
        o0.z = fmaxf(fmaf((float)yv[2] + u[2], sc, sh), 0.f);
        o0.w = fmaxf(fmaf((float)yv[3] + u[3], sc, sh), 0.f);
        o1.x = fmaxf(fmaf((float)yv[4] + u[4], sc, sh), 0.f);
        o1.y = fmaxf(fmaf((float)yv[5] + u[5], sc, sh), 0.f);
        o1.z = fmaxf(fmaf((float)yv[6] + u[6], sc, sh), 0.f);
        o1.w = fmaxf(fmaf((float)yv[7] + u[7], sc, sh), 0.f);
        *(float4*)(op + base) = o0;
        *(float4*)(op + base + 4) = o1;
    }
}

// ---------------------------------------------------------------------------
extern "C" void kernel_launch(void* const* d_in, const int* in_sizes, int n_in,
                              void* d_out, int out_size, void* d_ws, size_t ws_size,
                              hipStream_t stream) {
    const float* x      = (const float*)d_in[0];   // (8,256,128,128)
    const float* conv_w = (const float*)d_in[1];   // (256,1024)
    const float* gamma  = (const float*)d_in[2];   // (256,)
    const float* beta   = (const float*)d_in[3];   // (256,)
    float* out = (float*)d_out;

    char* ws = (char*)d_ws;
    // Wbf 512K | z 16M | stats 4K | cT 48M | y1 64M   (~129 MB)
    bf16*  Wbf   = (bf16*)ws;
    bf16*  z     = (bf16*)(ws + (512ll << 10));
    float* stats = (float*)(ws + (512ll << 10) + (16ll << 20));
    bf16*  cT    = (bf16*)(ws + (512ll << 10) + (16ll << 20) + 4096);
    bf16*  y1    = (bf16*)(ws + (512ll << 10) + (64ll << 20) + 4096);

    hipMemsetAsync(stats, 0, 4096, stream);
    prep_w<<<256, 256, 0, stream>>>(conv_w, Wbf);
    fused_x<<<2048, 256, 0, stream>>>(x, Wbf, cT, y1);
    gemm2<<<512, 256, 0, stream>>>(Wbf, cT, z);
    stats_k<<<2048, 256, 0, stream>>>(y1, z, stats);
    finalize_k<<<1, 256, 0, stream>>>(stats, gamma, beta);
    apply_k<<<2048, 256, 0, stream>>>(y1, z, stats, out);
}

// Round 5
// 346.657 us; speedup vs baseline: 1.1591x; 1.1591x over previous
//
#include <hip/hip_runtime.h>
#include <hip/hip_bf16.h>

typedef __bf16 bf16;
typedef __bf16 bf16x4 __attribute__((ext_vector_type(4)));
typedef __bf16 bf16x8 __attribute__((ext_vector_type(8)));
typedef float  f32x4  __attribute__((ext_vector_type(4)));

#define AS1 __attribute__((address_space(1)))
#define AS3 __attribute__((address_space(3)))

__device__ __forceinline__ void load16_to_lds(const bf16* g, bf16* l) {
    __builtin_amdgcn_global_load_lds((const AS1 unsigned int*)g,
                                     (AS3 unsigned int*)l, 16, 0, 0);
}

// ---------------------------------------------------------------------------
// prep_w: conv_w fp32 [o][1024] -> bf16 same layout. Must precede fused_x.
__global__ __launch_bounds__(256) void prep_w(const float* __restrict__ w,
                                              bf16* __restrict__ wb) {
    int idx = (blockIdx.x * 256 + threadIdx.x) * 4;   // grid 256
    const float4 v = *(const float4*)(w + idx);
    bf16x4 o; o[0]=(bf16)v.x; o[1]=(bf16)v.y; o[2]=(bf16)v.z; o[3]=(bf16)v.w;
    *(bf16x4*)(wb + idx) = o;
}

// ---------------------------------------------------------------------------
// tile layout: [row 0..63][264 bf16], 8-elem chunks XOR-swizzled by
// (row>>2)&7: phase1's scalar b16 writes drop from 8-way to ~2-way bank
// conflict (r4-verified: 8.4M -> 2.1M cyc). Readers apply the same XOR.
__device__ __forceinline__ int tix(int row, int chunk, int lo) {
    return row * 264 + (((chunk ^ ((row >> 2) & 7)) << 3) | lo);
}

// fused_x: per block (b, coarse row j, 32-wide w-tile):
//   phase1: x fp32 -> LDS tile [64 pos][256 c] bf16, two bursts of 8 float4
//           (32 VGPRs peak -- NO spill; r4's 16-burst + (256,4) spilled 130MB)
//   phase2: Haar details -> cT bf16 [mc][d*256+c]
//   phase3: y1 = W[:,0:256] . tile -- K=256 GEMM, W-frags from L2 with
//           depth-1 pipeline; barrier-free K-loop.
__global__ __launch_bounds__(256, 2) void fused_x(const float* __restrict__ x,
                                                  const bf16* __restrict__ W,
                                                  bf16* __restrict__ cT,
                                                  bf16* __restrict__ y1) {
    __shared__ bf16 tile[64 * 264];
    const int bid = blockIdx.x;               // grid 2048
    const int wt = bid & 3, j = (bid >> 2) & 63, b = bid >> 8;
    const int t = threadIdx.x;
    const int w0 = wt * 32;
    const int wave = t >> 6, lane = t & 63;
    const int quad = lane >> 4, l16 = lane & 15;
    const int wo = wave * 64;

    // phase1: two bursts of 8 independent float4 loads, then convert+write
    #pragma unroll
    for (int half = 0; half < 2; ++half) {
        float4 v[8];
        #pragma unroll
        for (int i = 0; i < 8; ++i) {
            int g = (half * 8 + i) * 256 + t;
            int c = g >> 4, rem = g & 15;
            int dlt = rem >> 3, w4 = rem & 7;
            v[i] = *(const float4*)(x +
                ((((size_t)b * 256 + c) * 128 + (2 * j + dlt)) * 128 + w0 + w4 * 4));
        }
        #pragma unroll
        for (int i = 0; i < 8; ++i) {
            int g = (half * 8 + i) * 256 + t;
            int c = g >> 4, rem = g & 15;
            int dlt = rem >> 3, w4 = rem & 7;
            int pos = dlt * 32 + w4 * 4;
            int cs = tix(pos, c >> 3, c & 7) - pos * 264;
            tile[(pos + 0) * 264 + cs] = (bf16)v[i].x;
            tile[(pos + 1) * 264 + cs] = (bf16)v[i].y;
            tile[(pos + 2) * 264 + cs] = (bf16)v[i].z;
            tile[(pos + 3) * 264 + cs] = (bf16)v[i].w;
        }
    }

    // prefetch W fragments for kk=0 (L2-resident; latency hidden by barrier
    // wait + phase2)
    bf16x8 wf_cur[4], wf_nxt[4];
    #pragma unroll
    for (int jj = 0; jj < 4; ++jj)
        wf_cur[jj] = *(const bf16x8*)(W +
            (size_t)(wo + jj * 16 + l16) * 1024 + quad * 8);

    __syncthreads();

    // phase2: Haar -> cT. 16 coarse cols * 32 c-chunks.
    #pragma unroll
    for (int i = 0; i < 2; ++i) {
        int q = i * 256 + t;
        int cq = q & 31, kc = q >> 5;
        bf16x8 vp = *(const bf16x8*)&tile[tix(2 * kc, cq, 0)];
        bf16x8 vq = *(const bf16x8*)&tile[tix(2 * kc + 1, cq, 0)];
        bf16x8 vr = *(const bf16x8*)&tile[tix(32 + 2 * kc, cq, 0)];
        bf16x8 vs = *(const bf16x8*)&tile[tix(33 + 2 * kc, cq, 0)];
        bf16x8 oh, ov, od;
        #pragma unroll
        for (int e = 0; e < 8; ++e) {
            float p = (float)vp[e], qq = (float)vq[e];
            float r = (float)vr[e], s = (float)vs[e];
            oh[e] = (bf16)(0.5f * (p + qq - r - s));
            ov[e] = (bf16)(0.5f * (p - qq + r - s));
            od[e] = (bf16)(0.5f * (p - qq - r + s));
        }
        size_t row = ((size_t)b * 4096 + j * 64 + wt * 16 + kc) * 768;
        *(bf16x8*)(cT + row + 0 * 256 + cq * 8) = oh;
        *(bf16x8*)(cT + row + 1 * 256 + cq * 8) = ov;
        *(bf16x8*)(cT + row + 2 * 256 + cq * 8) = od;
    }

    // phase3: wave = 64 pos x 64 o. MFMA(xf, wf): D.row=pos, D.col=o.
    f32x4 acc[4][4] = {};
    #pragma unroll
    for (int kk = 0; kk < 256; kk += 32) {
        if (kk < 224) {
            #pragma unroll
            for (int jj = 0; jj < 4; ++jj)
                wf_nxt[jj] = *(const bf16x8*)(W +
                    (size_t)(wo + jj * 16 + l16) * 1024 + kk + 32 + quad * 8);
        }
        bf16x8 xf[4];
        #pragma unroll
        for (int i2 = 0; i2 < 4; ++i2)
            xf[i2] = *(const bf16x8*)&tile[tix(i2 * 16 + l16,
                                               (kk >> 3) + quad, 0)];
        #pragma unroll
        for (int i2 = 0; i2 < 4; ++i2)
            #pragma unroll
            for (int jj = 0; jj < 4; ++jj)
                acc[i2][jj] = __builtin_amdgcn_mfma_f32_16x16x32_bf16(
                    xf[i2], wf_cur[jj], acc[i2][jj], 0, 0, 0);
        #pragma unroll
        for (int jj = 0; jj < 4; ++jj) wf_cur[jj] = wf_nxt[jj];
    }

    // epilogue: pos = i*16+quad*4+r (4 consecutive w), o = wo+jj*16+l16
    #pragma unroll
    for (int i = 0; i < 4; ++i) {
        int p = i * 16 + quad * 4;
        int h = 2 * j + (p >> 5), wc = w0 + (p & 31);
        #pragma unroll
        for (int jj = 0; jj < 4; ++jj) {
            int o = wo + jj * 16 + l16;
            bf16x4 vv;
            #pragma unroll
            for (int r = 0; r < 4; ++r) vv[r] = (bf16)acc[i][jj][r];
            *(bf16x4*)(y1 + ((size_t)b * 256 + o) * 16384 + h * 128 + wc) = vv;
        }
    }
}

// ---------------------------------------------------------------------------
// gemm2: z[o][mc] = W[:,256:1024] . cT, K=768. 128x128 tile; cT staged via
// global_load_lds; W-frags direct from L2 with depth-1 pipeline.
// Plain launch_bounds: (256,4) in r4 capped VGPR at 128 < ~140 live -> spill.
__global__ __launch_bounds__(256) void gemm2(const bf16* __restrict__ W,
                                             const bf16* __restrict__ cT,
                                             bf16* __restrict__ z) {
    __shared__ bf16 Xt[128 * 32];
    const int bid = blockIdx.x;               // grid 512
    const int m0 = (bid & 255) * 128, o0 = (bid >> 8) * 128;
    const int t = threadIdx.x;
    const int wave = t >> 6, lane = t & 63;
    const int quad = lane >> 4, l16 = lane & 15;
    const int wo = (wave >> 1) * 64, wm = (wave & 1) * 64;
    const int r_in = lane >> 2, cch = lane & 3;

    f32x4 acc[4][4] = {};
    const bf16* wbase = W + (size_t)o0 * 1024 + 256;
    const bf16* xbase = cT + (size_t)m0 * 768;

    bf16x8 af_cur[4], af_nxt[4];
    #pragma unroll
    for (int i = 0; i < 4; ++i)
        af_cur[i] = *(const bf16x8*)(wbase +
            (size_t)(wo + i * 16 + l16) * 1024 + quad * 8);

    for (int kk = 0; kk < 768; kk += 32) {
        #pragma unroll
        for (int i = 0; i < 2; ++i) {
            int rblk = wave * 2 + i;
            int row = rblk * 16 + r_in;
            load16_to_lds(xbase + (size_t)row * 768 + kk + cch * 8,
                          &Xt[rblk * 512 + lane * 8]);
        }
        __syncthreads();
        if (kk < 736) {
            #pragma unroll
            for (int i = 0; i < 4; ++i)
                af_nxt[i] = *(const bf16x8*)(wbase +
                    (size_t)(wo + i * 16 + l16) * 1024 + kk + 32 + quad * 8);
        }
        bf16x8 bfr[4];
        #pragma unroll
        for (int jj = 0; jj < 4; ++jj)
            bfr[jj] = *(const bf16x8*)&Xt[(wm + jj * 16 + l16) * 32 + quad * 8];
        #pragma unroll
        for (int i = 0; i < 4; ++i)
            #pragma unroll
            for (int jj = 0; jj < 4; ++jj)
                acc[i][jj] = __builtin_amdgcn_mfma_f32_16x16x32_bf16(
                    bfr[jj], af_cur[i], acc[i][jj], 0, 0, 0);
        __syncthreads();
        #pragma unroll
        for (int i = 0; i < 4; ++i) af_cur[i] = af_nxt[i];
    }

    #pragma unroll
    for (int i = 0; i < 4; ++i) {
        int o = o0 + wo + i * 16 + l16;
        #pragma unroll
        for (int jj = 0; jj < 4; ++jj) {
            int m = m0 + wm + jj * 16 + quad * 4;
            int bb = m >> 12, mp = m & 4095;
            bf16x4 vv;
            #pragma unroll
            for (int r = 0; r < 4; ++r) vv[r] = (bf16)acc[i][jj][r];
            *(bf16x4*)(z + ((size_t)bb * 256 + o) * 4096 + mp) = vv;
        }
    }
}

// ---------------------------------------------------------------------------
// Bilinear 2x upsample weights: 0.75/0.25 per axis, edge-clamped (== jax).
__device__ __forceinline__ void load_zplane(const bf16* zp, float* zs, int t) {
    for (int i = 0; i < 2; ++i) {
        int idx = (i * 256 + t) * 8;
        int j = idx >> 6, k = idx & 63;
        bf16x8 v = *(const bf16x8*)(zp + idx);
        #pragma unroll
        for (int e = 0; e < 8; ++e) zs[j * 65 + k + e] = (float)v[e];
    }
}

__device__ __forceinline__ void up8(const float* zs, int base, float* u) {
    int h = base >> 7, w0 = base & 127;
    int j0 = h >> 1;
    int jn = (h & 1) ? min(j0 + 1, 63) : max(j0 - 1, 0);
    int K = w0 >> 1;
    float z0[6], z1[6];
    #pragma unroll
    for (int d = 0; d < 6; ++d) {
        int kc = min(max(K - 1 + d, 0), 63);
        z0[d] = zs[j0 * 65 + kc];
        z1[d] = zs[jn * 65 + kc];
    }
    #pragma unroll
    for (int e = 0; e < 8; ++e) {
        int a = (e >> 1) + 1;
        int bb = (e & 1) ? a + 1 : a - 1;
        u[e] = 0.5625f * z0[a] + 0.1875f * (z0[bb] + z1[a]) + 0.0625f * z1[bb];
    }
}

__global__ __launch_bounds__(256) void stats_k(const bf16* __restrict__ y1,
                                               const bf16* __restrict__ z,
                                               float* __restrict__ stats) {
    __shared__ float zs[64 * 65];
    __shared__ float red[8];
    const int bid = blockIdx.x;               // grid 2048 = b*256 + o
    const int o = bid & 255, b = bid >> 8;
    const int t = threadIdx.x;
    const bf16* zp = z + ((size_t)b * 256 + o) * 4096;
    const bf16* yp = y1 + ((size_t)b * 256 + o) * 16384;
    load_zplane(zp, zs, t);
    __syncthreads();
    float s = 0.f, ss = 0.f;
    for (int i = 0; i < 8; ++i) {
        int base = (i * 256 + t) * 8;
        float u[8];
        up8(zs, base, u);
        bf16x8 yv = *(const bf16x8*)(yp + base);
        #pragma unroll
        for (int e = 0; e < 8; ++e) {
            float y = (float)yv[e] + u[e];
            s += y; ss += y * y;
        }
    }
    #pragma unroll
    for (int off = 32; off > 0; off >>= 1) {
        s += __shfl_down(s, off);
        ss += __shfl_down(ss, off);
    }
    if ((t & 63) == 0) { red[t >> 6] = s; red[4 + (t >> 6)] = ss; }
    __syncthreads();
    if (t == 0) {
        atomicAdd(&stats[o],       red[0] + red[1] + red[2] + red[3]);
        atomicAdd(&stats[256 + o], red[4] + red[5] + red[6] + red[7]);
    }
}

// apply_k: finalize folded in (mean/var/scale/shift recomputed per block from
// the raw sums -- 2 scalar loads + ~6 ops, cheaper than a dispatch).
__global__ __launch_bounds__(256) void apply_k(const bf16* __restrict__ y1,
                                               const bf16* __restrict__ z,
                                               const float* __restrict__ stats,
                                               const float* __restrict__ gamma,
                                               const float* __restrict__ beta,
                                               float* __restrict__ out) {
    __shared__ float zs[64 * 65];
    const int bid = blockIdx.x;
    const int o = bid & 255, b = bid >> 8;
    const int t = threadIdx.x;
    const bf16* zp = z + ((size_t)b * 256 + o) * 4096;
    const bf16* yp = y1 + ((size_t)b * 256 + o) * 16384;
    float* op = out + ((size_t)b * 256 + o) * 16384;
    const float n = 131072.f;
    float mean = stats[o] / n;
    float var = stats[256 + o] / n - mean * mean;
    float sc = rsqrtf(var + 1e-5f) * gamma[o];
    float sh = beta[o] - mean * sc;
    load_zplane(zp, zs, t);
    __syncthreads();
    for (int i = 0; i < 8; ++i) {
        int base = (i * 256 + t) * 8;
        float u[8];
        up8(zs, base, u);
        bf16x8 yv = *(const bf16x8*)(yp + base);
        float4 o0, o1;
        o0.x = fmaxf(fmaf((float)yv[0] + u[0], sc, sh), 0.f);
        o0.y = fmaxf(fmaf((float)yv[1] + u[1], sc, sh), 0.f);
        o0.z = fmaxf(fmaf((float)yv[2] + u[2], sc, sh), 0.f);
        o0.w = fmaxf(fmaf((float)yv[3] + u[3], sc, sh), 0.f);
        o1.x = fmaxf(fmaf((float)yv[4] + u[4], sc, sh), 0.f);
        o1.y = fmaxf(fmaf((float)yv[5] + u[5], sc, sh), 0.f);
        o1.z = fmaxf(fmaf((float)yv[6] + u[6], sc, sh), 0.f);
        o1.w = fmaxf(fmaf((float)yv[7] + u[7], sc, sh), 0.f);
        *(float4*)(op + base) = o0;
        *(float4*)(op + base + 4) = o1;
    }
}

// ---------------------------------------------------------------------------
extern "C" void kernel_launch(void* const* d_in, const int* in_sizes, int n_in,
                              void* d_out, int out_size, void* d_ws, size_t ws_size,
                              hipStream_t stream) {
    const float* x      = (const float*)d_in[0];   // (8,256,128,128)
    const float* conv_w = (const float*)d_in[1];   // (256,1024)
    const float* gamma  = (const float*)d_in[2];   // (256,)
    const float* beta   = (const float*)d_in[3];   // (256,)
    float* out = (float*)d_out;

    char* ws = (char*)d_ws;
    // Wbf 512K | z 16M | stats 4K | cT 48M | y1 64M   (~129 MB)
    bf16*  Wbf   = (bf16*)ws;
    bf16*  z     = (bf16*)(ws + (512ll << 10));
    float* stats = (float*)(ws + (512ll << 10) + (16ll << 20));
    bf16*  cT    = (bf16*)(ws + (512ll << 10) + (16ll << 20) + 4096);
    bf16*  y1    = (bf16*)(ws + (512ll << 10) + (64ll << 20) + 4096);

    hipMemsetAsync(stats, 0, 4096, stream);
    prep_w<<<256, 256, 0, stream>>>(conv_w, Wbf);
    fused_x<<<2048, 256, 0, stream>>>(x, Wbf, cT, y1);
    gemm2<<<512, 256, 0, stream>>>(Wbf, cT, z);
    stats_k<<<2048, 256, 0, stream>>>(y1, z, stats);
    apply_k<<<2048, 256, 0, stream>>>(y1, z, stats, gamma, beta, out);
}